// Round 1
// baseline (435.636 us; speedup 1.0000x reference)
//
#include <hip/hip_runtime.h>

#define N 8192
#define D 256

// ---------------- Kernel 1: x = h @ W  (fp32, 64x64 tile, 4x4 microtile) ---
#define BM 64
#define BN 64
#define BK 16

__global__ __launch_bounds__(256) void gemm_hw(const float* __restrict__ A,
                                               const float* __restrict__ B,
                                               float* __restrict__ C) {
    __shared__ float As[BK][BM];  // transposed A tile: As[k][m]
    __shared__ float Bs[BK][BN];

    const int bm = blockIdx.x * BM;
    const int bn = blockIdx.y * BN;
    const int tid = threadIdx.x;

    const int tm = (tid / 16) * 4;  // 0..60
    const int tn = (tid % 16) * 4;  // 0..60

    float acc[4][4] = {};

    // A-load indices: each thread loads one float4 of h
    const int ar = tid / 4;         // 0..63 (row within tile)
    const int ak = (tid % 4) * 4;   // 0,4,8,12 (k within tile)
    // B-load indices
    const int bk = tid / 16;        // 0..15
    const int bnn = (tid % 16) * 4; // 0..60

    for (int k0 = 0; k0 < D; k0 += BK) {
        float4 av = *(const float4*)&A[(size_t)(bm + ar) * D + k0 + ak];
        float4 bv = *(const float4*)&B[(size_t)(k0 + bk) * D + bn + bnn];
        As[ak + 0][ar] = av.x;
        As[ak + 1][ar] = av.y;
        As[ak + 2][ar] = av.z;
        As[ak + 3][ar] = av.w;
        *(float4*)&Bs[bk][bnn] = bv;
        __syncthreads();
#pragma unroll
        for (int kk = 0; kk < BK; ++kk) {
            float4 a = *(const float4*)&As[kk][tm];
            float4 b = *(const float4*)&Bs[kk][tn];
            const float ae[4] = {a.x, a.y, a.z, a.w};
            const float be[4] = {b.x, b.y, b.z, b.w};
#pragma unroll
            for (int r = 0; r < 4; ++r)
#pragma unroll
                for (int c = 0; c < 4; ++c)
                    acc[r][c] = fmaf(ae[r], be[c], acc[r][c]);
        }
        __syncthreads();
    }
#pragma unroll
    for (int r = 0; r < 4; ++r) {
        float4 o = make_float4(acc[r][0], acc[r][1], acc[r][2], acc[r][3]);
        *(float4*)&C[(size_t)(bm + tm + r) * D + bn + tn] = o;
    }
}

// ---------------- Kernel 2: el[i] = x[i].a_l, er[i] = x[i].a_r -------------
__global__ __launch_bounds__(256) void rowdot(const float* __restrict__ x,
                                              const float* __restrict__ a_l,
                                              const float* __restrict__ a_r,
                                              float* __restrict__ el,
                                              float* __restrict__ er) {
    const int wave = threadIdx.x >> 6;
    const int lane = threadIdx.x & 63;
    const int i = blockIdx.x * 4 + wave;

    float4 xv = *(const float4*)&x[(size_t)i * D + lane * 4];
    float4 lv = *(const float4*)&a_l[lane * 4];
    float4 rv = *(const float4*)&a_r[lane * 4];

    float dl = xv.x * lv.x + xv.y * lv.y + xv.z * lv.z + xv.w * lv.w;
    float dr = xv.x * rv.x + xv.y * rv.y + xv.z * rv.z + xv.w * rv.w;
#pragma unroll
    for (int off = 32; off > 0; off >>= 1) {
        dl += __shfl_down(dl, off, 64);
        dr += __shfl_down(dr, off, 64);
    }
    if (lane == 0) {
        el[i] = dl;
        er[i] = dr;
    }
}

// ---------------- Kernel 3: fused attention + aggregate --------------------
// One block per row i. Scan adj row in chunks of 1024 cols, compact nonzero
// (j, w) pairs into LDS, then each thread d accumulates dim d across entries.
#define CHUNK 1024

__global__ __launch_bounds__(256) void gat_agg(const float* __restrict__ adj,
                                               const float* __restrict__ x,
                                               const float* __restrict__ el,
                                               const float* __restrict__ er,
                                               const float* __restrict__ bias,
                                               float* __restrict__ out) {
    __shared__ int s_idx[CHUNK];
    __shared__ float s_w[CHUNK];
    __shared__ unsigned s_cnt;
    __shared__ float s_denom;

    const int i = blockIdx.x;
    const int tid = threadIdx.x;

    if (tid == 0) {
        s_cnt = 0;
        s_denom = 0.0f;
    }
    const float eli = el[i];
    float acc = 0.0f;
    const float* __restrict__ arow = adj + (size_t)i * N;
    __syncthreads();

    for (int c = 0; c < N; c += CHUNK) {
        float4 av = *(const float4*)&arow[c + tid * 4];
        const float ve[4] = {av.x, av.y, av.z, av.w};
#pragma unroll
        for (int u = 0; u < 4; ++u) {
            if (ve[u] != 0.0f) {
                const int j = c + tid * 4 + u;
                const float s = eli + er[j];
                const float lr = s > 0.0f ? s : 0.2f * s;
                const float w = __expf(lr);
                const unsigned p = atomicAdd(&s_cnt, 1u);
                s_idx[p] = j;
                s_w[p] = w;
                atomicAdd(&s_denom, w);
            }
        }
        __syncthreads();
        const int cnt = (int)s_cnt;
        for (int k = 0; k < cnt; ++k) {
            acc = fmaf(s_w[k], x[(size_t)s_idx[k] * D + tid], acc);
        }
        __syncthreads();
        if (tid == 0) s_cnt = 0;
        __syncthreads();
    }

    const float denom = fmaxf(s_denom, 1e-12f);
    out[(size_t)i * D + tid] = acc / denom + bias[tid];
}

// ---------------------------------------------------------------------------
extern "C" void kernel_launch(void* const* d_in, const int* in_sizes, int n_in,
                              void* d_out, int out_size, void* d_ws, size_t ws_size,
                              hipStream_t stream) {
    const float* h = (const float*)d_in[0];
    const float* adj = (const float*)d_in[1];
    const float* weight = (const float*)d_in[2];
    const float* a_l = (const float*)d_in[3];
    const float* a_r = (const float*)d_in[4];
    const float* bias = (const float*)d_in[5];
    float* out = (float*)d_out;

    // workspace layout: x [N*D f32] | el [N f32] | er [N f32]
    float* x = (float*)d_ws;
    float* el = x + (size_t)N * D;
    float* er = el + N;

    dim3 gemm_grid(N / BM, D / BN);
    gemm_hw<<<gemm_grid, 256, 0, stream>>>(h, weight, x);

    rowdot<<<N / 4, 256, 0, stream>>>(x, a_l, a_r, el, er);

    gat_agg<<<N, 256, 0, stream>>>(adj, x, el, er, bias, out);
}